// Round 2
// baseline (376.875 us; speedup 1.0000x reference)
//
#include <hip/hip_runtime.h>
#include <stdint.h>

// ---------- types ----------
typedef __attribute__((ext_vector_type(8))) __bf16 bf16x8;
typedef __attribute__((ext_vector_type(4))) float   f32x4;

__device__ __forceinline__ float bf2f(unsigned short u) {
    union { unsigned int i; float f; } v; v.i = ((unsigned int)u) << 16; return v.f;
}
__device__ __forceinline__ unsigned short f2bf(float f) {  // round-to-nearest-even
    unsigned int x = __builtin_bit_cast(unsigned int, f);
    x += 0x7FFFu + ((x >> 16) & 1u);
    return (unsigned short)(x >> 16);
}

// ---------- fp32 -> bf16 cast (vectorized, grid-stride) ----------
__global__ __launch_bounds__(256) void cast_kernel(const float* __restrict__ src,
                                                   unsigned short* __restrict__ dst, int n4) {
    int i = blockIdx.x * blockDim.x + threadIdx.x;
    int stride = gridDim.x * blockDim.x;
    const float4* s4 = (const float4*)src;
    ushort4* d4 = (ushort4*)dst;
    for (; i < n4; i += stride) {
        float4 v = s4[i];
        ushort4 o;
        o.x = f2bf(v.x); o.y = f2bf(v.y); o.z = f2bf(v.z); o.w = f2bf(v.w);
        d4[i] = o;
    }
}

// ---------- GEMM: C[M,NTOT] = A[M,K] * W[NTOT,K]^T  (both bf16, row-major, K inner) ----------
// 128x128 tile, BK=64, 256 threads = 4 waves (2x2), 16x16x32 bf16 MFMA.
// MODE 0: += bias (split at col 256), store bf16.  MODE 1: relu, store fp32.
template<int NTOT, int MODE>
__global__ __launch_bounds__(256, 2)
void gemm_bt(const unsigned short* __restrict__ A,
             const unsigned short* __restrict__ W,
             const float* __restrict__ bias0,
             const float* __restrict__ bias1,
             unsigned short* __restrict__ outb,
             float* __restrict__ outf,
             int M, int K) {
    __shared__ unsigned short As[128 * 64];
    __shared__ unsigned short Bs[128 * 64];

    const int t    = threadIdx.x;
    const int wave = t >> 6;
    const int lane = t & 63;
    const int MT   = M >> 7;
    const int mt   = blockIdx.x % MT;   // mt fastest: consecutive blocks share W (L2), stream A
    const int nt   = blockIdx.x / MT;
    const int wr   = wave >> 1;         // 2x2 wave grid, each wave owns 64x64
    const int wc   = wave & 1;

    const size_t aBase = (size_t)(mt * 128) * K;
    const size_t bBase = (size_t)(nt * 128) * K;
    const int rowA = t >> 3;            // 0..31  (8 threads x 16B per 128B row of 64 bf16)
    const int colE = (t & 7) * 8;       // element offset within BK=64

    f32x4 acc[4][4];
#pragma unroll
    for (int m = 0; m < 4; ++m)
#pragma unroll
        for (int n = 0; n < 4; ++n) acc[m][n] = f32x4{0.f, 0.f, 0.f, 0.f};

    const int lr = lane & 15;
    const int lk = (lane >> 4) * 8;

    for (int kt = 0; kt < K; kt += 64) {
        // stage A,B tiles: 4 x global_load_lds (width 16) each, linear LDS layout
#pragma unroll
        for (int i = 0; i < 4; ++i) {
            const unsigned short* ga = A + aBase + (size_t)(i * 32 + rowA) * K + kt + colE;
            const unsigned short* gb = W + bBase + (size_t)(i * 32 + rowA) * K + kt + colE;
            unsigned short* la = As + i * 2048 + wave * 512;  // wave-uniform base; HW adds lane*16B
            unsigned short* lb = Bs + i * 2048 + wave * 512;
            __builtin_amdgcn_global_load_lds((const __attribute__((address_space(1))) void*)ga,
                                             (__attribute__((address_space(3))) void*)la, 16, 0, 0);
            __builtin_amdgcn_global_load_lds((const __attribute__((address_space(1))) void*)gb,
                                             (__attribute__((address_space(3))) void*)lb, 16, 0, 0);
        }
        __syncthreads();
#pragma unroll
        for (int kk = 0; kk < 64; kk += 32) {
            bf16x8 af[4], bfr[4];
#pragma unroll
            for (int m = 0; m < 4; ++m)
                af[m] = *reinterpret_cast<const bf16x8*>(&As[(wr * 64 + m * 16 + lr) * 64 + kk + lk]);
#pragma unroll
            for (int n = 0; n < 4; ++n)
                bfr[n] = *reinterpret_cast<const bf16x8*>(&Bs[(wc * 64 + n * 16 + lr) * 64 + kk + lk]);
#pragma unroll
            for (int m = 0; m < 4; ++m)
#pragma unroll
                for (int n = 0; n < 4; ++n)
                    acc[m][n] = __builtin_amdgcn_mfma_f32_16x16x32_bf16(af[m], bfr[n], acc[m][n], 0, 0, 0);
        }
        __syncthreads();
    }

    // epilogue: C/D layout col = lane&15, row = (lane>>4)*4 + reg
    const int rowOff = (lane >> 4) * 4;
#pragma unroll
    for (int n = 0; n < 4; ++n) {
        const int gc = nt * 128 + wc * 64 + n * 16 + lr;
        float bv = 0.f;
        if (MODE == 0) bv = (gc < 256) ? bias0[gc] : bias1[gc - 256];
#pragma unroll
        for (int m = 0; m < 4; ++m) {
            const int gr = mt * 128 + wr * 64 + m * 16 + rowOff;
#pragma unroll
            for (int r = 0; r < 4; ++r) {
                float v = acc[m][n][r] + bv;
                if (MODE == 0) outb[(size_t)(gr + r) * NTOT + gc] = f2bf(v);
                else           outf[(size_t)(gr + r) * NTOT + gc] = fmaxf(v, 0.f);
            }
        }
    }
}

// ---------- per-batch: sim -> mask -> softmax -> relation + agg (in-place over x_bf16) ----------
__global__ __launch_bounds__(256)
void relation_kernel(const unsigned short* __restrict__ TP,   // [M,512] bf16: theta|phi
                     const float* __restrict__ boxes,         // [M,4]
                     unsigned short* __restrict__ xagg,       // [M,1024] bf16 in, agg out (aliased)
                     float* __restrict__ relout) {            // [BT,12,12] fp32
    __shared__ float th[12][260];   // +4 pad: banks (4n+r)%32 -> conflict-free
    __shared__ float ph[12][260];
    __shared__ unsigned short xls[12 * 1024];
    __shared__ float cx[12], cy[12];
    __shared__ float sim[12][12];
    __shared__ float rel[12][12];

    const int b = blockIdx.x;
    const int t = threadIdx.x;

    if (t < 12) {
        const float* bx = boxes + ((size_t)b * 12 + t) * 4;
        cx[t] = (bx[0] + bx[2]) * 0.5f;
        cy[t] = (bx[1] + bx[3]) * 0.5f;
    }
    // stage theta/phi (12x512 bf16 = 768 x 16B)
    const uint4* tp4 = (const uint4*)(TP + (size_t)b * 6144);
    for (int c = t; c < 768; c += 256) {
        uint4 v = tp4[c];
        const unsigned short* pv = (const unsigned short*)&v;
        const int n = c >> 6;
        const int c0 = (c & 63) << 3;
        if (c0 < 256) {
#pragma unroll
            for (int j = 0; j < 8; ++j) th[n][c0 + j] = bf2f(pv[j]);
        } else {
#pragma unroll
            for (int j = 0; j < 8; ++j) ph[n][c0 - 256 + j] = bf2f(pv[j]);
        }
    }
    // stage x tile (12x1024 bf16 = 1536 x 16B) BEFORE overwriting with agg
    const uint4* x4 = (const uint4*)(xagg + (size_t)b * 12288);
    uint4* xl4 = (uint4*)xls;
    for (int c = t; c < 1536; c += 256) xl4[c] = x4[c];
    __syncthreads();

    if (t < 144) {
        const int n = t / 12, m = t - (t / 12) * 12;
        float a = 0.f;
#pragma unroll 8
        for (int r = 0; r < 256; ++r) a += th[n][r] * ph[m][r];
        const float dx = cx[n] - cx[m], dy = cy[n] - cy[m];
        const float d2 = dx * dx + dy * dy;
        const float thr = 31.4f;  // POS_THRESHOLD * OW
        sim[n][m] = (d2 > thr * thr) ? -__builtin_inff() : a * 0.0625f;  // /sqrt(256)
    }
    __syncthreads();

    if (t < 12) {  // softmax over m; diagonal always unmasked -> mx finite
        float mx = -__builtin_inff();
#pragma unroll
        for (int m = 0; m < 12; ++m) mx = fmaxf(mx, sim[t][m]);
        float e[12]; float s = 0.f;
#pragma unroll
        for (int m = 0; m < 12; ++m) { e[m] = expf(sim[t][m] - mx); s += e[m]; }
        const float inv = 1.f / s;
#pragma unroll
        for (int m = 0; m < 12; ++m) {
            const float r = e[m] * inv;
            rel[t][m] = r;
            relout[(size_t)b * 144 + t * 12 + m] = r;
        }
    }
    __syncthreads();

    // agg[n][f] = sum_m rel[n][m] * x[m][f]  -> bf16, in place
    unsigned short* aggp = xagg + (size_t)b * 12288;
    for (int f = t; f < 1024; f += 256) {
        float xv[12];
#pragma unroll
        for (int m = 0; m < 12; ++m) xv[m] = bf2f(xls[m * 1024 + f]);
#pragma unroll
        for (int n = 0; n < 12; ++n) {
            float a = 0.f;
#pragma unroll
            for (int m = 0; m < 12; ++m) a += rel[n][m] * xv[m];
            aggp[n * 1024 + f] = f2bf(a);
        }
    }
}

// ---------- launcher ----------
extern "C" void kernel_launch(void* const* d_in, const int* in_sizes, int n_in,
                              void* d_out, int out_size, void* d_ws, size_t ws_size,
                              hipStream_t stream) {
    const float* x     = (const float*)d_in[0];  // [4096,12,1024]
    const float* boxes = (const float*)d_in[1];  // [49152,4]
    const float* Wth   = (const float*)d_in[2];  // [256,1024]
    const float* bth   = (const float*)d_in[3];  // [256]
    const float* Wph   = (const float*)d_in[4];  // [256,1024]
    const float* bph   = (const float*)d_in[5];  // [256]
    const float* Wg    = (const float*)d_in[6];  // [1024,1024]
    float* out = (float*)d_out;                  // 49152*1024 out | 4096*144 relation

    const int M = 49152, K = 1024;
    const size_t XE = (size_t)M * K;             // 50331648 elems

    char* ws = (char*)d_ws;
    unsigned short* xb   = (unsigned short*)ws;                         // bf16 x, later agg (in place)
    unsigned short* TP   = (unsigned short*)(ws + 100663296);           // [M,512] bf16 theta|phi
    unsigned short* Wcat = (unsigned short*)(ws + 150994944);           // [512,1024] bf16
    unsigned short* Wgb  = (unsigned short*)(ws + 152043520);           // [1024,1024] bf16
    // total ws use: 154,140,672 bytes

    cast_kernel<<<2048, 256, 0, stream>>>(x, xb, (int)(XE / 4));
    cast_kernel<<<128, 256, 0, stream>>>(Wth, Wcat, 262144 / 4);
    cast_kernel<<<128, 256, 0, stream>>>(Wph, Wcat + 262144, 262144 / 4);
    cast_kernel<<<256, 256, 0, stream>>>(Wg, Wgb, 1048576 / 4);

    gemm_bt<512, 0><<<dim3((M / 128) * 4), 256, 0, stream>>>(xb, Wcat, bth, bph, TP, nullptr, M, K);

    relation_kernel<<<4096, 256, 0, stream>>>(TP, boxes, xb, out + XE);

    gemm_bt<1024, 1><<<dim3((M / 128) * 8), 256, 0, stream>>>(xb, Wgb, nullptr, nullptr, nullptr, out, M, K);
}

// Round 3
// 342.716 us; speedup vs baseline: 1.0997x; 1.0997x over previous
//
#include <hip/hip_runtime.h>
#include <stdint.h>

// ---------- types ----------
typedef __attribute__((ext_vector_type(8))) __bf16 bf16x8;
typedef __attribute__((ext_vector_type(4))) float   f32x4;

__device__ __forceinline__ float bf2f(unsigned short u) {
    union { unsigned int i; float f; } v; v.i = ((unsigned int)u) << 16; return v.f;
}
__device__ __forceinline__ unsigned short f2bf(float f) {  // round-to-nearest-even
    unsigned int x = __builtin_bit_cast(unsigned int, f);
    x += 0x7FFFu + ((x >> 16) & 1u);
    return (unsigned short)(x >> 16);
}

// ---------- fp32 -> bf16 cast (vectorized, grid-stride) ----------
__global__ __launch_bounds__(256) void cast_kernel(const float* __restrict__ src,
                                                   unsigned short* __restrict__ dst, int n4) {
    int i = blockIdx.x * blockDim.x + threadIdx.x;
    int stride = gridDim.x * blockDim.x;
    const float4* s4 = (const float4*)src;
    ushort4* d4 = (ushort4*)dst;
    for (; i < n4; i += stride) {
        float4 v = s4[i];
        ushort4 o;
        o.x = f2bf(v.x); o.y = f2bf(v.y); o.z = f2bf(v.z); o.w = f2bf(v.w);
        d4[i] = o;
    }
}

// ---------- GEMM: C[M,NTOT] = A[M,K] * W[NTOT,K]^T  (bf16 in, fp32 accum) ----------
// 256x128 tile, BK=64, 512 threads = 8 waves (4Mx2N, each wave 64x64 output).
// 3-stage LDS pipeline (depth-2 prefetch, counted vmcnt), chunk-XOR swizzled LDS,
// XCD-aware block mapping, LDS-staged coalesced epilogue.
// MODE 0: += bias (split at col 256), store bf16.  MODE 1: relu, store fp32.
template<int NTOT, int MODE, int NTI>
__global__ __launch_bounds__(512, 2)
void gemm_bt(const unsigned short* __restrict__ A,
             const unsigned short* __restrict__ W,
             const float* __restrict__ bias0,
             const float* __restrict__ bias1,
             unsigned short* __restrict__ outb,
             float* __restrict__ outf) {
    constexpr int K  = 1024;
    constexpr int NT = K / 64;           // 16 K-tiles
    // per buffer: A 256x64 (16384 sh) + B 128x64 (8192 sh) = 24576 shorts = 48 KB; x3 = 144 KB
    __shared__ unsigned short lds[3 * 24576];

    const int t    = threadIdx.x;
    const int wave = t >> 6;
    const int lane = t & 63;

    // XCD-aware bijective swizzle: xcd = bid&7 (HW round-robin), per-XCD nt-fastest.
    const int bid = blockIdx.x;
    const int xcd = bid & 7;
    const int j   = bid >> 3;            // 0 .. 24*NTI-1 per XCD
    const int mt  = xcd * 24 + j / NTI;  // 192 M-tiles total
    const int nt  = j % NTI;

    const int wr = wave >> 1;            // 0..3 : rows wr*64..
    const int wc = wave & 1;             // 0..1 : cols wc*64..

    const size_t aBase = (size_t)mt * 256 * K;
    const size_t bBase = (size_t)nt * 128 * K;

    // staging geometry: per block-wide gload_lds instr: 512 thr x 16B = 64 rows of 128B
    const int srow = t >> 3;                         // 0..63
    const int scol = ((t & 7) ^ (srow & 7)) << 3;    // swizzled source col (elements)

    const unsigned short* gA = A + aBase + scol;
    const unsigned short* gB = W + bBase + scol;

    auto STAGE = [&](int kt, int buf) {
        unsigned short* lb = lds + buf * 24576;
#pragma unroll
        for (int i = 0; i < 4; ++i)
            __builtin_amdgcn_global_load_lds(
                (const __attribute__((address_space(1))) void*)(gA + (size_t)(i * 64 + srow) * K + kt),
                (__attribute__((address_space(3))) void*)(lb + i * 4096 + wave * 512), 16, 0, 0);
#pragma unroll
        for (int i = 0; i < 2; ++i)
            __builtin_amdgcn_global_load_lds(
                (const __attribute__((address_space(1))) void*)(gB + (size_t)(i * 64 + srow) * K + kt),
                (__attribute__((address_space(3))) void*)(lb + 16384 + i * 4096 + wave * 512), 16, 0, 0);
    };

    f32x4 acc[4][4];
#pragma unroll
    for (int m = 0; m < 4; ++m)
#pragma unroll
        for (int n = 0; n < 4; ++n) acc[m][n] = f32x4{0.f, 0.f, 0.f, 0.f};

    const int lr  = lane & 15;
    const int lkc = lane >> 4;           // 0..3 -> col chunk within K-half
    const int rsw = lr & 7;              // read-side swizzle key (row&7 == lr&7)

    // prologue: tiles 0,1 in flight (12 loads/wave)
    STAGE(0, 0);
    STAGE(64, 1);

    int cur = 0;
    for (int tt = 0; tt < NT; ++tt) {
        int b2 = cur + 2; if (b2 >= 3) b2 -= 3;
        if (tt + 2 < NT) STAGE((tt + 2) * 64, b2);

        if (tt < NT - 2)       asm volatile("s_waitcnt vmcnt(12)" ::: "memory");
        else if (tt == NT - 2) asm volatile("s_waitcnt vmcnt(6)"  ::: "memory");
        else                   asm volatile("s_waitcnt vmcnt(0)"  ::: "memory");
        __builtin_amdgcn_s_barrier();
        asm volatile("" ::: "memory");

        const unsigned short* LA = lds + cur * 24576;
        const unsigned short* LB = LA + 16384;
#pragma unroll
        for (int kk2 = 0; kk2 < 2; ++kk2) {
            const int gch = kk2 * 4 + lkc;           // global col chunk 0..7
            const int sch = (gch ^ rsw) << 3;        // swizzled element col
            bf16x8 af[4], bfr[4];
#pragma unroll
            for (int m = 0; m < 4; ++m)
                af[m] = *reinterpret_cast<const bf16x8*>(&LA[(wr * 64 + m * 16 + lr) * 64 + sch]);
#pragma unroll
            for (int n = 0; n < 4; ++n)
                bfr[n] = *reinterpret_cast<const bf16x8*>(&LB[(wc * 64 + n * 16 + lr) * 64 + sch]);
            __builtin_amdgcn_s_setprio(1);
#pragma unroll
            for (int m = 0; m < 4; ++m)
#pragma unroll
                for (int n = 0; n < 4; ++n)
                    acc[m][n] = __builtin_amdgcn_mfma_f32_16x16x32_bf16(af[m], bfr[n], acc[m][n], 0, 0, 0);
            __builtin_amdgcn_s_setprio(0);
        }

        asm volatile("" ::: "memory");
        __builtin_amdgcn_s_barrier();
        asm volatile("" ::: "memory");
        cur = cur + 1; if (cur >= 3) cur -= 3;
    }

    // -------- epilogue: acc -> LDS (padded) -> coalesced global stores --------
    const int rowOff = (lane >> 4) * 4;  // C/D: col = lane&15, row = rowOff + r
    if (MODE == 1) {
        float* lf = (float*)lds;         // per wave: 64 x 68 floats (stride 68 = pad 4)
#pragma unroll
        for (int n = 0; n < 4; ++n)
#pragma unroll
            for (int m = 0; m < 4; ++m)
#pragma unroll
                for (int r = 0; r < 4; ++r)
                    lf[wave * 4352 + (m * 16 + rowOff + r) * 68 + (n * 16 + lr)] =
                        fmaxf(acc[m][n][r], 0.f);
        __syncthreads();
#pragma unroll
        for (int it = 0; it < 16; ++it) {            // 256x128 fp32 tile = 128 KB
            const int flat = it * 8192 + t * 16;     // byte offset in tile
            const int row  = flat >> 9;              // /512 (128 cols * 4B)
            const int col  = (flat & 511) >> 2;
            const int wv   = ((row >> 6) << 1) + (col >> 6);
            float4 v = *reinterpret_cast<const float4*>(&lf[wv * 4352 + (row & 63) * 68 + (col & 63)]);
            *reinterpret_cast<float4*>(outf + (size_t)(mt * 256 + row) * NTOT + nt * 128 + col) = v;
        }
    } else {
        unsigned short* lu = lds;        // per wave: 64 x 72 shorts (stride 72 = pad 8)
#pragma unroll
        for (int n = 0; n < 4; ++n) {
            const int gc = nt * 128 + wc * 64 + n * 16 + lr;
            const float bv = (gc < 256) ? bias0[gc] : bias1[gc - 256];
#pragma unroll
            for (int m = 0; m < 4; ++m)
#pragma unroll
                for (int r = 0; r < 4; ++r)
                    lu[wave * 4608 + (m * 16 + rowOff + r) * 72 + (n * 16 + lr)] =
                        f2bf(acc[m][n][r] + bv);
        }
        __syncthreads();
#pragma unroll
        for (int it = 0; it < 8; ++it) {             // 256x128 bf16 tile = 64 KB
            const int flat = it * 8192 + t * 16;     // byte offset in tile
            const int row  = flat >> 8;              // /256 (128 cols * 2B)
            const int col  = (flat & 255) >> 1;
            const int wv   = ((row >> 6) << 1) + (col >> 6);
            uint4 v = *reinterpret_cast<const uint4*>(&lu[wv * 4608 + (row & 63) * 72 + (col & 63)]);
            *reinterpret_cast<uint4*>(outb + (size_t)(mt * 256 + row) * NTOT + nt * 128 + col) = v;
        }
    }
}

// ---------- per-batch: sim -> mask -> softmax -> relation + agg (in-place over x_bf16) ----------
__global__ __launch_bounds__(256)
void relation_kernel(const unsigned short* __restrict__ TP,   // [M,512] bf16: theta|phi
                     const float* __restrict__ boxes,         // [M,4]
                     unsigned short* __restrict__ xagg,       // [M,1024] bf16 in, agg out (aliased)
                     float* __restrict__ relout) {            // [BT,12,12] fp32
    __shared__ float th[12][260];
    __shared__ float ph[12][260];
    __shared__ unsigned short xls[12 * 1024];
    __shared__ float cx[12], cy[12];
    __shared__ float sim[12][12];
    __shared__ float rel[12][12];

    const int b = blockIdx.x;
    const int t = threadIdx.x;

    if (t < 12) {
        const float* bx = boxes + ((size_t)b * 12 + t) * 4;
        cx[t] = (bx[0] + bx[2]) * 0.5f;
        cy[t] = (bx[1] + bx[3]) * 0.5f;
    }
    const uint4* tp4 = (const uint4*)(TP + (size_t)b * 6144);
    for (int c = t; c < 768; c += 256) {
        uint4 v = tp4[c];
        const unsigned short* pv = (const unsigned short*)&v;
        const int n = c >> 6;
        const int c0 = (c & 63) << 3;
        if (c0 < 256) {
#pragma unroll
            for (int jj = 0; jj < 8; ++jj) th[n][c0 + jj] = bf2f(pv[jj]);
        } else {
#pragma unroll
            for (int jj = 0; jj < 8; ++jj) ph[n][c0 - 256 + jj] = bf2f(pv[jj]);
        }
    }
    const uint4* x4 = (const uint4*)(xagg + (size_t)b * 12288);
    uint4* xl4 = (uint4*)xls;
    for (int c = t; c < 1536; c += 256) xl4[c] = x4[c];
    __syncthreads();

    if (t < 144) {
        const int n = t / 12, m = t - (t / 12) * 12;
        float a = 0.f;
#pragma unroll 8
        for (int r = 0; r < 256; ++r) a += th[n][r] * ph[m][r];
        const float dx = cx[n] - cx[m], dy = cy[n] - cy[m];
        const float d2 = dx * dx + dy * dy;
        const float thr = 31.4f;  // POS_THRESHOLD * OW
        sim[n][m] = (d2 > thr * thr) ? -__builtin_inff() : a * 0.0625f;
    }
    __syncthreads();

    if (t < 12) {
        float mx = -__builtin_inff();
#pragma unroll
        for (int m = 0; m < 12; ++m) mx = fmaxf(mx, sim[t][m]);
        float e[12]; float s = 0.f;
#pragma unroll
        for (int m = 0; m < 12; ++m) { e[m] = expf(sim[t][m] - mx); s += e[m]; }
        const float inv = 1.f / s;
#pragma unroll
        for (int m = 0; m < 12; ++m) {
            const float r = e[m] * inv;
            rel[t][m] = r;
            relout[(size_t)b * 144 + t * 12 + m] = r;
        }
    }
    __syncthreads();

    unsigned short* aggp = xagg + (size_t)b * 12288;
    for (int f = t; f < 1024; f += 256) {
        float xv[12];
#pragma unroll
        for (int m = 0; m < 12; ++m) xv[m] = bf2f(xls[m * 1024 + f]);
#pragma unroll
        for (int n = 0; n < 12; ++n) {
            float a = 0.f;
#pragma unroll
            for (int m = 0; m < 12; ++m) a += rel[n][m] * xv[m];
            aggp[n * 1024 + f] = f2bf(a);
        }
    }
}

// ---------- launcher ----------
extern "C" void kernel_launch(void* const* d_in, const int* in_sizes, int n_in,
                              void* d_out, int out_size, void* d_ws, size_t ws_size,
                              hipStream_t stream) {
    const float* x     = (const float*)d_in[0];  // [4096,12,1024]
    const float* boxes = (const float*)d_in[1];  // [49152,4]
    const float* Wth   = (const float*)d_in[2];  // [256,1024]
    const float* bth   = (const float*)d_in[3];  // [256]
    const float* Wph   = (const float*)d_in[4];  // [256,1024]
    const float* bph   = (const float*)d_in[5];  // [256]
    const float* Wg    = (const float*)d_in[6];  // [1024,1024]
    float* out = (float*)d_out;                  // 49152*1024 out | 4096*144 relation

    const int M = 49152;
    const size_t XE = (size_t)M * 1024;

    char* ws = (char*)d_ws;
    unsigned short* xb   = (unsigned short*)ws;                 // bf16 x, later agg (in place)
    unsigned short* TP   = (unsigned short*)(ws + 100663296);   // [M,512] bf16 theta|phi
    unsigned short* Wcat = (unsigned short*)(ws + 150994944);   // [512,1024] bf16
    unsigned short* Wgb  = (unsigned short*)(ws + 152043520);   // [1024,1024] bf16

    cast_kernel<<<2048, 256, 0, stream>>>(x, xb, (int)(XE / 4));
    cast_kernel<<<128, 256, 0, stream>>>(Wth, Wcat, 262144 / 4);
    cast_kernel<<<128, 256, 0, stream>>>(Wph, Wcat + 262144, 262144 / 4);
    cast_kernel<<<256, 256, 0, stream>>>(Wg, Wgb, 1048576 / 4);

    // M-tiles = 192 (24 per XCD); grid = 192 * NTI
    gemm_bt<512, 0, 4><<<dim3(192 * 4), 512, 0, stream>>>(xb, Wcat, bth, bph, TP, nullptr);

    relation_kernel<<<4096, 256, 0, stream>>>(TP, boxes, xb, out + XE);

    gemm_bt<1024, 1, 8><<<dim3(192 * 8), 512, 0, stream>>>(xb, Wgb, nullptr, nullptr, nullptr, out);
}

// Round 4
// 315.230 us; speedup vs baseline: 1.1956x; 1.0872x over previous
//
#include <hip/hip_runtime.h>
#include <stdint.h>

// ---------- types ----------
typedef __attribute__((ext_vector_type(8))) __bf16 bf16x8;
typedef __attribute__((ext_vector_type(4))) float   f32x4;

__device__ __forceinline__ float bf2f(unsigned short u) {
    union { unsigned int i; float f; } v; v.i = ((unsigned int)u) << 16; return v.f;
}
__device__ __forceinline__ unsigned short f2bf(float f) {  // round-to-nearest-even
    unsigned int x = __builtin_bit_cast(unsigned int, f);
    x += 0x7FFFu + ((x >> 16) & 1u);
    return (unsigned short)(x >> 16);
}

// ---------- fp32 -> bf16 cast (vectorized, grid-stride) ----------
__global__ __launch_bounds__(256) void cast_kernel(const float* __restrict__ src,
                                                   unsigned short* __restrict__ dst, int n4) {
    int i = blockIdx.x * blockDim.x + threadIdx.x;
    int stride = gridDim.x * blockDim.x;
    const float4* s4 = (const float4*)src;
    ushort4* d4 = (ushort4*)dst;
    for (; i < n4; i += stride) {
        float4 v = s4[i];
        ushort4 o;
        o.x = f2bf(v.x); o.y = f2bf(v.y); o.z = f2bf(v.z); o.w = f2bf(v.w);
        d4[i] = o;
    }
}

// ---------- GEMM: C[M,NTOT] = A[M,K] * W[NTOT,K]^T  (bf16 in, fp32 accum) ----------
// 256x256 tile, BK=64, 512 threads = 8 waves (2M x 4N), per-wave output 128x64.
// 2-buffer LDS (128 KB), 4 phases/K-tile, half-tile staging, counted vmcnt(2),
// chunk-XOR swizzle (0 conflicts), XCD-aware mapping.
// MODE 0: += bias (split at col 256), store bf16 via LDS-coalesced epilogue.
// MODE 1: relu, store fp32 direct.
template<int NTOT, int MODE, int NTI>
__global__ __launch_bounds__(512, 2)
void gemm_bt(const unsigned short* __restrict__ A,
             const unsigned short* __restrict__ W,
             const float* __restrict__ bias0,
             const float* __restrict__ bias1,
             unsigned short* __restrict__ outb,
             float* __restrict__ outf) {
    constexpr int K  = 1024;
    constexpr int NT = 16;                 // K-tiles of 64
    // 2 buffers x (A 256x64 + B 256x64) shorts = 65536 shorts = 128 KB
    __shared__ unsigned short lds[65536];

    const int t    = threadIdx.x;
    const int wave = t >> 6;
    const int lane = t & 63;

    const int bid = blockIdx.x;
    const int xcd = bid & 7;               // HW round-robins blocks over 8 XCDs
    const int j   = bid >> 3;
    const int mt  = xcd * 24 + j / NTI;    // 192 M-tiles, 24 per XCD
    const int nt  = j % NTI;

    const int wr = wave >> 2;              // 0..1 : M half (rows wr*128..)
    const int wc = wave & 3;               // 0..3 : N quarter (cols wc*64..)

    const size_t aBase = (size_t)mt * 256 * K;
    const size_t bBase = (size_t)nt * 256 * K;

    // staging: one gload_lds instr covers 64 rows x 128B; swizzled source col
    const int srow = t >> 3;                          // 0..63
    const int scol = ((t & 7) ^ (srow & 7)) << 3;     // element offset
    const unsigned short* gA = A + aBase + (size_t)srow * K + scol;
    const unsigned short* gB = W + bBase + (size_t)srow * K + scol;

    // half 0: A rows 0-127, 1: A rows 128-255, 2: B rows 0-127, 3: B rows 128-255
    auto STAGE_HALF = [&](int tile, int half) {
        unsigned short* lb = lds + (tile & 1) * 32768 + (half >> 1) * 16384;
        const unsigned short* gp = (half >> 1) ? gB : gA;
        const int g0 = (half & 1) * 2;
        const int kt = tile * 64;
#pragma unroll
        for (int g = 0; g < 2; ++g)
            __builtin_amdgcn_global_load_lds(
                (const __attribute__((address_space(1))) void*)(gp + (size_t)(g0 + g) * 64 * K + kt),
                (__attribute__((address_space(3))) void*)(lb + (g0 + g) * 4096 + wave * 512), 16, 0, 0);
    };

    const int lr  = lane & 15;
    const int lkc = lane >> 4;
    auto LDA = [&](int buf, int mi, int kk) -> bf16x8 {
        const int row = wr * 128 + mi * 16 + lr;
        const int ch  = (kk * 4 + lkc) ^ (row & 7);
        return *reinterpret_cast<const bf16x8*>(&lds[buf * 32768 + row * 64 + ch * 8]);
    };
    auto LDB = [&](int buf, int ni, int kk) -> bf16x8 {
        const int row = wc * 64 + ni * 16 + lr;
        const int ch  = (kk * 4 + lkc) ^ (row & 7);
        return *reinterpret_cast<const bf16x8*>(&lds[buf * 32768 + 16384 + row * 64 + ch * 8]);
    };

    f32x4 acc[8][4];
#pragma unroll
    for (int m = 0; m < 8; ++m)
#pragma unroll
        for (int n = 0; n < 4; ++n) acc[m][n] = f32x4{0.f, 0.f, 0.f, 0.f};

    // prologue: tile0 fully + tile1 half0  (10 loads in flight)
    STAGE_HALF(0, 0); STAGE_HALF(0, 1); STAGE_HALF(0, 2); STAGE_HALF(0, 3);
    STAGE_HALF(1, 0);

    bf16x8 af[4][2], bfr[4][2];

    for (int tt = 0; tt < NT; ++tt) {
        const int buf = tt & 1;

        // ---- phase 0: gate, read Q0 frags (A m0-3, B n0-1), stage h1-h3(tt+1), MFMA Q0 ----
        if (tt == NT - 1) asm volatile("s_waitcnt vmcnt(0)" ::: "memory");
        else              asm volatile("s_waitcnt vmcnt(2)" ::: "memory");
        __builtin_amdgcn_s_barrier();
        asm volatile("" ::: "memory");
#pragma unroll
        for (int m = 0; m < 4; ++m) { af[m][0] = LDA(buf, m, 0); af[m][1] = LDA(buf, m, 1); }
#pragma unroll
        for (int n = 0; n < 2; ++n) { bfr[n][0] = LDB(buf, n, 0); bfr[n][1] = LDB(buf, n, 1); }
        if (tt + 1 < NT) { STAGE_HALF(tt + 1, 1); STAGE_HALF(tt + 1, 2); STAGE_HALF(tt + 1, 3); }
        __builtin_amdgcn_s_setprio(1);
#pragma unroll
        for (int m = 0; m < 4; ++m)
#pragma unroll
            for (int n = 0; n < 2; ++n)
#pragma unroll
                for (int kk = 0; kk < 2; ++kk)
                    acc[m][n] = __builtin_amdgcn_mfma_f32_16x16x32_bf16(af[m][kk], bfr[n][kk], acc[m][n], 0, 0, 0);
        __builtin_amdgcn_s_setprio(0);
        asm volatile("" ::: "memory");

        // ---- phase 1: read B n2-3, barrier, MFMA Q1 (m0-3 x n2-3) ----
#pragma unroll
        for (int n = 0; n < 2; ++n) { bfr[2 + n][0] = LDB(buf, 2 + n, 0); bfr[2 + n][1] = LDB(buf, 2 + n, 1); }
        asm volatile("" ::: "memory");
        __builtin_amdgcn_s_barrier();
        asm volatile("" ::: "memory");
        __builtin_amdgcn_s_setprio(1);
#pragma unroll
        for (int m = 0; m < 4; ++m)
#pragma unroll
            for (int n = 0; n < 2; ++n)
#pragma unroll
                for (int kk = 0; kk < 2; ++kk)
                    acc[m][2 + n] = __builtin_amdgcn_mfma_f32_16x16x32_bf16(af[m][kk], bfr[2 + n][kk], acc[m][2 + n], 0, 0, 0);
        __builtin_amdgcn_s_setprio(0);
        asm volatile("" ::: "memory");

        // ---- phase 2: read A m4-7, barrier, MFMA Q2 (m4-7 x n0-1) ----
#pragma unroll
        for (int m = 0; m < 4; ++m) { af[m][0] = LDA(buf, 4 + m, 0); af[m][1] = LDA(buf, 4 + m, 1); }
        asm volatile("" ::: "memory");
        __builtin_amdgcn_s_barrier();
        asm volatile("" ::: "memory");
        __builtin_amdgcn_s_setprio(1);
#pragma unroll
        for (int m = 0; m < 4; ++m)
#pragma unroll
            for (int n = 0; n < 2; ++n)
#pragma unroll
                for (int kk = 0; kk < 2; ++kk)
                    acc[4 + m][n] = __builtin_amdgcn_mfma_f32_16x16x32_bf16(af[m][kk], bfr[n][kk], acc[4 + m][n], 0, 0, 0);
        __builtin_amdgcn_s_setprio(0);
        asm volatile("" ::: "memory");

        // ---- phase 3: barrier (A h0 fully consumed), stage h0(tt+2), MFMA Q3 (m4-7 x n2-3) ----
        __builtin_amdgcn_s_barrier();
        asm volatile("" ::: "memory");
        if (tt + 2 < NT) STAGE_HALF(tt + 2, 0);
        __builtin_amdgcn_s_setprio(1);
#pragma unroll
        for (int m = 0; m < 4; ++m)
#pragma unroll
            for (int n = 0; n < 2; ++n)
#pragma unroll
                for (int kk = 0; kk < 2; ++kk)
                    acc[4 + m][2 + n] = __builtin_amdgcn_mfma_f32_16x16x32_bf16(af[m][kk], bfr[2 + n][kk], acc[4 + m][2 + n], 0, 0, 0);
        __builtin_amdgcn_s_setprio(0);
        asm volatile("" ::: "memory");
    }

    // -------- epilogue --------
    const int rowOff = (lane >> 4) * 4;   // C/D: col = lane&15, row = rowOff + r
    if (MODE == 1) {
#pragma unroll
        for (int m = 0; m < 8; ++m)
#pragma unroll
            for (int n = 0; n < 4; ++n)
#pragma unroll
                for (int r = 0; r < 4; ++r)
                    outf[(size_t)(mt * 256 + wr * 128 + m * 16 + rowOff + r) * NTOT
                         + nt * 256 + wc * 64 + n * 16 + lr] = fmaxf(acc[m][n][r], 0.f);
    } else {
        unsigned short* lu = lds;         // 8 regions x 64 x 72 shorts
#pragma unroll
        for (int mh = 0; mh < 2; ++mh) {
            __syncthreads();
#pragma unroll
            for (int mq = 0; mq < 4; ++mq)
#pragma unroll
                for (int n = 0; n < 4; ++n) {
                    const int gc = nt * 256 + wc * 64 + n * 16 + lr;
                    const float bv = (gc < 256) ? bias0[gc] : bias1[gc - 256];
#pragma unroll
                    for (int r = 0; r < 4; ++r)
                        lu[wave * 4608 + (mq * 16 + rowOff + r) * 72 + n * 16 + lr] =
                            f2bf(acc[mh * 4 + mq][n][r] + bv);
                }
            __syncthreads();
#pragma unroll
            for (int it = 0; it < 8; ++it) {          // 128 rows x 256 cols bf16
                const int flat = it * 4096 + t * 8;   // shorts
                const int rp   = flat >> 8;           // 0..127
                const int col  = flat & 255;
                const int R    = (rp >> 6) * 128 + mh * 64 + (rp & 63);
                const int reg  = (rp >> 6) * 4 + (col >> 6);
                uint4 v = *reinterpret_cast<const uint4*>(&lu[reg * 4608 + (rp & 63) * 72 + (col & 63)]);
                *reinterpret_cast<uint4*>(outb + (size_t)(mt * 256 + R) * NTOT + nt * 256 + col) = v;
            }
        }
    }
}

// ---------- per-batch: sim -> mask -> softmax -> relation + agg (in-place over x_bf16) ----------
__global__ __launch_bounds__(256)
void relation_kernel(const unsigned short* __restrict__ TP,   // [M,512] bf16: theta|phi
                     const float* __restrict__ boxes,         // [M,4]
                     unsigned short* __restrict__ xagg,       // [M,1024] bf16 in, agg out (aliased)
                     float* __restrict__ relout) {            // [BT,12,12] fp32
    __shared__ float th[12][260];
    __shared__ float ph[12][260];
    __shared__ unsigned short xls[12 * 1024];
    __shared__ float cx[12], cy[12];
    __shared__ float sim[12][12];
    __shared__ float rel[12][12];

    const int b = blockIdx.x;
    const int t = threadIdx.x;

    if (t < 12) {
        const float* bx = boxes + ((size_t)b * 12 + t) * 4;
        cx[t] = (bx[0] + bx[2]) * 0.5f;
        cy[t] = (bx[1] + bx[3]) * 0.5f;
    }
    const uint4* tp4 = (const uint4*)(TP + (size_t)b * 6144);
    for (int c = t; c < 768; c += 256) {
        uint4 v = tp4[c];
        const unsigned short* pv = (const unsigned short*)&v;
        const int n = c >> 6;
        const int c0 = (c & 63) << 3;
        if (c0 < 256) {
#pragma unroll
            for (int jj = 0; jj < 8; ++jj) th[n][c0 + jj] = bf2f(pv[jj]);
        } else {
#pragma unroll
            for (int jj = 0; jj < 8; ++jj) ph[n][c0 - 256 + jj] = bf2f(pv[jj]);
        }
    }
    const uint4* x4 = (const uint4*)(xagg + (size_t)b * 12288);
    uint4* xl4 = (uint4*)xls;
    for (int c = t; c < 1536; c += 256) xl4[c] = x4[c];
    __syncthreads();

    if (t < 144) {
        const int n = t / 12, m = t - (t / 12) * 12;
        float a = 0.f;
#pragma unroll 8
        for (int r = 0; r < 256; ++r) a += th[n][r] * ph[m][r];
        const float dx = cx[n] - cx[m], dy = cy[n] - cy[m];
        const float d2 = dx * dx + dy * dy;
        const float thr = 31.4f;  // POS_THRESHOLD * OW
        sim[n][m] = (d2 > thr * thr) ? -__builtin_inff() : a * 0.0625f;
    }
    __syncthreads();

    if (t < 12) {
        float mx = -__builtin_inff();
#pragma unroll
        for (int m = 0; m < 12; ++m) mx = fmaxf(mx, sim[t][m]);
        float e[12]; float s = 0.f;
#pragma unroll
        for (int m = 0; m < 12; ++m) { e[m] = expf(sim[t][m] - mx); s += e[m]; }
        const float inv = 1.f / s;
#pragma unroll
        for (int m = 0; m < 12; ++m) {
            const float r = e[m] * inv;
            rel[t][m] = r;
            relout[(size_t)b * 144 + t * 12 + m] = r;
        }
    }
    __syncthreads();

    unsigned short* aggp = xagg + (size_t)b * 12288;
    for (int f = t; f < 1024; f += 256) {
        float xv[12];
#pragma unroll
        for (int m = 0; m < 12; ++m) xv[m] = bf2f(xls[m * 1024 + f]);
#pragma unroll
        for (int n = 0; n < 12; ++n) {
            float a = 0.f;
#pragma unroll
            for (int m = 0; m < 12; ++m) a += rel[n][m] * xv[m];
            aggp[n * 1024 + f] = f2bf(a);
        }
    }
}

// ---------- launcher ----------
extern "C" void kernel_launch(void* const* d_in, const int* in_sizes, int n_in,
                              void* d_out, int out_size, void* d_ws, size_t ws_size,
                              hipStream_t stream) {
    const float* x     = (const float*)d_in[0];  // [4096,12,1024]
    const float* boxes = (const float*)d_in[1];  // [49152,4]
    const float* Wth   = (const float*)d_in[2];  // [256,1024]
    const float* bth   = (const float*)d_in[3];  // [256]
    const float* Wph   = (const float*)d_in[4];  // [256,1024]
    const float* bph   = (const float*)d_in[5];  // [256]
    const float* Wg    = (const float*)d_in[6];  // [1024,1024]
    float* out = (float*)d_out;                  // 49152*1024 out | 4096*144 relation

    const int M = 49152;
    const size_t XE = (size_t)M * 1024;

    char* ws = (char*)d_ws;
    unsigned short* xb   = (unsigned short*)ws;                 // bf16 x, later agg (in place)
    unsigned short* TP   = (unsigned short*)(ws + 100663296);   // [M,512] bf16 theta|phi
    unsigned short* Wcat = (unsigned short*)(ws + 150994944);   // [512,1024] bf16
    unsigned short* Wgb  = (unsigned short*)(ws + 152043520);   // [1024,1024] bf16

    cast_kernel<<<2048, 256, 0, stream>>>(x, xb, (int)(XE / 4));
    cast_kernel<<<128, 256, 0, stream>>>(Wth, Wcat, 262144 / 4);
    cast_kernel<<<128, 256, 0, stream>>>(Wph, Wcat + 262144, 262144 / 4);
    cast_kernel<<<256, 256, 0, stream>>>(Wg, Wgb, 1048576 / 4);

    // 192 M-tiles (24/XCD); grid = 192 * NTI, NTI = NTOT/256
    gemm_bt<512, 0, 2><<<dim3(192 * 2), 512, 0, stream>>>(xb, Wcat, bth, bph, TP, nullptr);

    relation_kernel<<<4096, 256, 0, stream>>>(TP, boxes, xb, out + XE);

    gemm_bt<1024, 1, 4><<<dim3(192 * 4), 512, 0, stream>>>(xb, Wgb, nullptr, nullptr, nullptr, out);
}